// Round 8
// baseline (203.447 us; speedup 1.0000x reference)
//
#include <hip/hip_runtime.h>
#include <hip/hip_bf16.h>

typedef float f32x4 __attribute__((ext_vector_type(4)));
typedef short short8 __attribute__((ext_vector_type(8)));
typedef short short4v __attribute__((ext_vector_type(4)));

#define MFMA(a, b, c) __builtin_amdgcn_mfma_f32_16x16x32_bf16((a), (b), (c), 0, 0, 0)

#if __has_builtin(__builtin_amdgcn_mfma_f32_16x16x16_bf16)
#define MFMA16(a, b, c) __builtin_amdgcn_mfma_f32_16x16x16_bf16((a), (b), (c), 0, 0, 0)
#elif __has_builtin(__builtin_amdgcn_mfma_f32_16x16x16bf16_1k)
#define MFMA16(a, b, c) __builtin_amdgcn_mfma_f32_16x16x16bf16_1k((a), (b), (c), 0, 0, 0)
#else
static __device__ __forceinline__ f32x4 mfma16_asm(short4v a, short4v b, f32x4 c) {
    asm volatile("v_mfma_f32_16x16x16_bf16 %0, %1, %2, %0" : "+v"(c) : "v"(a), "v"(b));
    return c;
}
#define MFMA16(a, b, c) mfma16_asm((a), (b), (c))
#endif

#if __has_builtin(__builtin_amdgcn_exp2f)
#define EXP2(x) __builtin_amdgcn_exp2f(x)
#else
#define EXP2(x) exp2f(x)
#endif

#define B_  2
#define N_  2048
#define C_  1024
#define H_  16
#define HD_ 64
#define M_  (B_ * N_)   // 4096

// softmax scale (1/8) * log2(e), folded into Q at qkv epilogue
#define QSCALE 0.18033688011112042f

typedef const __attribute__((address_space(1))) void* gp_t;
typedef __attribute__((address_space(3))) void* sp_t;
#define GLL16(g, s) __builtin_amdgcn_global_load_lds((gp_t)(const void*)(g), (sp_t)(void*)(s), 16, 0, 0)

__device__ __forceinline__ short f2bf(float f) {
    union { float fv; unsigned u; } v; v.fv = f;
    unsigned r = v.u + 0x7fffu + ((v.u >> 16) & 1u);  // RNE
    return (short)(r >> 16);
}
__device__ __forceinline__ unsigned pack_rne(float a, float b) {
    return (unsigned)(unsigned short)f2bf(a) | ((unsigned)(unsigned short)f2bf(b) << 16);
}

// ---------------- fp32 -> bf16 conversion pass ----------------
__global__ __launch_bounds__(256) void convert_kernel(
    const float* __restrict__ x,  const float* __restrict__ wq,
    const float* __restrict__ wk, const float* __restrict__ wv,
    const float* __restrict__ wo, short* __restrict__ dst)
{
    size_t e = ((size_t)blockIdx.x * 256 + threadIdx.x) * 8;
    const float* src; size_t off;
    if (e < 4194304)      { src = x;  off = e; }
    else if (e < 5242880) { src = wq; off = e - 4194304; }
    else if (e < 6291456) { src = wk; off = e - 5242880; }
    else if (e < 7340032) { src = wv; off = e - 6291456; }
    else                  { src = wo; off = e - 7340032; }
    float4 a = *(const float4*)(src + off);
    float4 b = *(const float4*)(src + off + 4);
    short8 s;
    s[0] = f2bf(a.x); s[1] = f2bf(a.y); s[2] = f2bf(a.z); s[3] = f2bf(a.w);
    s[4] = f2bf(b.x); s[5] = f2bf(b.y); s[6] = f2bf(b.z); s[7] = f2bf(b.w);
    *(short8*)(dst + e) = s;
}

// ---------------- fused QKV GEMM ----------------
// 128x128 tile, BK=32, double-buffered GLL16 staging with ONE barrier per
// K-iteration (R7 attn pattern): prefetch slab k+1 issues before compute of
// slab k, so the barrier's vmcnt(0) drain waits on loads that had a full
// compute phase in flight. Q gets QSCALE folded.
__global__ __launch_bounds__(256) void qkv_gemm(
    const short* __restrict__ xb, const short* __restrict__ Wb,
    short* __restrict__ Qb, short* __restrict__ Kb, short* __restrict__ Vt)
{
    const int m0 = blockIdx.x * 128;
    const int n0 = blockIdx.y * 128;
    __shared__ short As[2][128 * 32];   // 8 KB each
    __shared__ short Bs[2][128 * 32];
    const int tid  = threadIdx.x;
    const int wave = tid >> 6, lane = tid & 63;
    const int quad = lane >> 4, l16 = lane & 15;
    const int wr = (wave >> 1) * 64, wc = (wave & 1) * 64;

    // fixed per-thread staging geometry: slots f0=tid*8, f1=(tid+256)*8
    const int f0 = tid * 8,        r0 = f0 >> 5, cc0 = f0 & 31;
    const int f1 = (tid + 256) * 8, r1 = f1 >> 5, cc1 = f1 & 31;
    const short* xA0 = xb + (size_t)(m0 + r0) * C_ + cc0;
    const short* xA1 = xb + (size_t)(m0 + r1) * C_ + cc1;
    const short* wA0 = Wb + (size_t)(n0 + r0) * C_ + cc0;
    const short* wA1 = Wb + (size_t)(n0 + r1) * C_ + cc1;

    f32x4 acc[4][4] = {};

    // stage slab 0
    GLL16(xA0, &As[0][f0]); GLL16(xA1, &As[0][f1]);
    GLL16(wA0, &Bs[0][f0]); GLL16(wA1, &Bs[0][f1]);
    __syncthreads();

    for (int kt = 0; kt < C_ / 32; ++kt) {
        const int cur = kt & 1;
        if (kt + 1 < C_ / 32) {
            int kk = (kt + 1) * 32;
            GLL16(xA0 + kk, &As[cur ^ 1][f0]); GLL16(xA1 + kk, &As[cur ^ 1][f1]);
            GLL16(wA0 + kk, &Bs[cur ^ 1][f0]); GLL16(wA1 + kk, &Bs[cur ^ 1][f1]);
        }
        const short* Sa = As[cur];
        const short* Sb = Bs[cur];
        short8 af[4], bf[4];
        #pragma unroll
        for (int mi = 0; mi < 4; ++mi) af[mi] = *(const short8*)&Sa[(wr + mi * 16 + l16) * 32 + quad * 8];
        #pragma unroll
        for (int ni = 0; ni < 4; ++ni) bf[ni] = *(const short8*)&Sb[(wc + ni * 16 + l16) * 32 + quad * 8];
        #pragma unroll
        for (int mi = 0; mi < 4; ++mi)
        #pragma unroll
        for (int ni = 0; ni < 4; ++ni)
            acc[mi][ni] = MFMA(af[mi], bf[ni], acc[mi][ni]);
        __syncthreads();   // one barrier/iter: drains prefetch, guards buffer reuse
    }

    const int which = n0 >> 10;        // block-uniform: 0=Q 1=K 2=V
    const int nb = n0 & 1023;
    #pragma unroll
    for (int mi = 0; mi < 4; ++mi)
    #pragma unroll
    for (int ni = 0; ni < 4; ++ni)
    #pragma unroll
    for (int r = 0; r < 4; ++r) {
        int m  = m0 + wr + mi * 16 + quad * 4 + r;
        int cc = nb + wc + ni * 16 + l16;
        float av = acc[mi][ni][r];
        if (which == 0) av *= QSCALE;
        short bv = f2bf(av);
        int bb = m >> 11, ns = m & (N_ - 1);
        int h = cc >> 6, d = cc & 63;
        size_t bh = (size_t)(bb * H_ + h);
        if (which == 0)      Qb[(bh * N_ + ns) * HD_ + d] = bv;
        else if (which == 1) Kb[(bh * N_ + ns) * HD_ + d] = bv;
        else                 Vt[(bh * HD_ + d) * N_ + ns] = bv;  // V transposed
    }
}

// ---------------- Flash attention (R7 exact — measured 59.5 us) ----------
__global__ __launch_bounds__(256, 2) void attn_kernel(
    const short* __restrict__ Qb, const short* __restrict__ Kb,
    const short* __restrict__ Vt, short* __restrict__ Ob)
{
    const int bh = blockIdx.y;
    const int b = bh >> 4, h = bh & (H_ - 1);
    const int i0 = blockIdx.x * 128;
    __shared__ short Qs[128 * 64];      // 16 KB
    __shared__ short Ks[2][64 * 64];    // 16 KB
    __shared__ short Vs[2][64 * 64];    // 16 KB, Vs[d][j]
    const int tid  = threadIdx.x;
    const int wave = tid >> 6, lane = tid & 63;
    const int quad = lane >> 4, l16 = lane & 15;
    const int sw = l16 & 7;             // frag-read swizzle key (row&7 == l16&7)

    const short* Qg = Qb + ((size_t)bh * N_ + i0) * HD_;
    const short* Kg = Kb + (size_t)bh * N_ * HD_;
    const short* Vg = Vt + (size_t)bh * HD_ * N_;

    const int row0 = tid >> 3,  c0 = (tid & 7) ^ (row0 & 7);
    const int row1 = row0 + 32, c1 = (tid & 7) ^ (row1 & 7);
    const short* KgA0 = Kg + row0 * HD_ + c0 * 8;
    const short* KgA1 = Kg + row1 * HD_ + c1 * 8;
    const short* VgA0 = Vg + (size_t)row0 * N_ + c0 * 8;
    const short* VgA1 = Vg + (size_t)row1 * N_ + c1 * 8;

    #pragma unroll
    for (int it = 0; it < 4; ++it) {
        int s = it * 256 + tid;
        int row = s >> 3, c = (s & 7) ^ (row & 7);
        GLL16(Qg + row * HD_ + c * 8, &Qs[s * 8]);
    }
    GLL16(KgA0, &Ks[0][tid * 8]);
    GLL16(KgA1, &Ks[0][(tid + 256) * 8]);
    GLL16(VgA0, &Vs[0][tid * 8]);
    GLL16(VgA1, &Vs[0][(tid + 256) * 8]);
    __syncthreads();

    short8 qf[2][2];
    #pragma unroll
    for (int s = 0; s < 2; ++s) {
        int row = (wave * 32 + s * 16 + l16) * 64;
        qf[s][0] = *(const short8*)&Qs[row + ((quad ^ sw) * 8)];
        qf[s][1] = *(const short8*)&Qs[row + (((quad + 4) ^ sw) * 8)];
    }

    f32x4 o[2][4] = {};
    float lrow[2] = {0.f, 0.f};

    for (int jt = 0; jt < N_ / 64; ++jt) {
        const int cur = jt & 1;
        if (jt + 1 < N_ / 64) {
            int j1 = (jt + 1) * 64;
            GLL16(KgA0 + (size_t)j1 * HD_, &Ks[cur ^ 1][tid * 8]);
            GLL16(KgA1 + (size_t)j1 * HD_, &Ks[cur ^ 1][(tid + 256) * 8]);
            GLL16(VgA0 + j1, &Vs[cur ^ 1][tid * 8]);
            GLL16(VgA1 + j1, &Vs[cur ^ 1][(tid + 256) * 8]);
        }
        const short* Kc = Ks[cur];
        const short* Vc = Vs[cur];

        #pragma unroll
        for (int ni = 0; ni < 4; ++ni) {
            int krow = (ni * 16 + l16) * 64;
            short8 kf0 = *(const short8*)&Kc[krow + ((quad ^ sw) * 8)];
            short8 kf1 = *(const short8*)&Kc[krow + (((quad + 4) ^ sw) * 8)];
            short4v pp[2];
            #pragma unroll
            for (int s = 0; s < 2; ++s) {
                f32x4 st = {0.f, 0.f, 0.f, 0.f};
                st = MFMA(kf0, qf[s][0], st);
                st = MFMA(kf1, qf[s][1], st);   // S^T[j=16ni+4q+r][i=strip+l16]
                union { float f; unsigned u; } e0, e1, e2, e3;
                e0.f = EXP2(st[0]); e1.f = EXP2(st[1]);
                e2.f = EXP2(st[2]); e3.f = EXP2(st[3]);
                lrow[s] += (e0.f + e1.f) + (e2.f + e3.f);
                unsigned w0 = (e0.u >> 16) | (e1.u & 0xffff0000u);
                unsigned w1 = (e2.u >> 16) | (e3.u & 0xffff0000u);
                union { unsigned u[2]; short4v s4; } pk;
                pk.u[0] = w0; pk.u[1] = w1;
                pp[s] = pk.s4;
            }
            #pragma unroll
            for (int di = 0; di < 4; ++di) {
                int vrow = (di * 16 + l16) * 64;
                short4v vf = *(const short4v*)&Vc[vrow + (((ni * 2 + (quad >> 1)) ^ sw) * 8) + (quad & 1) * 4];
                o[0][di] = MFMA16(vf, pp[0], o[0][di]);
                o[1][di] = MFMA16(vf, pp[1], o[1][di]);
            }
        }
        __syncthreads();
    }

    #pragma unroll
    for (int s = 0; s < 2; ++s) {
        float l = lrow[s];
        l += __shfl_xor(l, 16, 64);
        l += __shfl_xor(l, 32, 64);
        float inv = 1.f / l;
        int ig = i0 + wave * 32 + s * 16 + l16;
        size_t base = ((size_t)(b * N_ + ig)) * C_ + h * HD_;
        #pragma unroll
        for (int di = 0; di < 4; ++di) {
            unsigned p01 = pack_rne(o[s][di][0] * inv, o[s][di][1] * inv);
            unsigned p23 = pack_rne(o[s][di][2] * inv, o[s][di][3] * inv);
            *(unsigned*)&Ob[base + di * 16 + quad * 4]     = p01;
            *(unsigned*)&Ob[base + di * 16 + quad * 4 + 2] = p23;
        }
    }
}

// ---------------- Output projection ----------------
// 64x128 tile, BK=32, double-buffered single-barrier staging (R7 pattern).
__global__ __launch_bounds__(256) void proj_gemm(
    const short* __restrict__ Ob, const short* __restrict__ wob,
    const float* __restrict__ bo, float* __restrict__ out)
{
    const int m0 = blockIdx.x * 64;
    const int n0 = blockIdx.y * 128;
    __shared__ short As[2][64 * 32];    // 4 KB each
    __shared__ short Bs[2][128 * 32];   // 8 KB each
    const int tid  = threadIdx.x;
    const int wave = tid >> 6, lane = tid & 63;
    const int quad = lane >> 4, l16 = lane & 15;
    const int wr = (wave >> 1) * 32, wc = (wave & 1) * 64;

    const int f0 = tid * 8,         r0 = f0 >> 5, cc0 = f0 & 31;
    const int f1 = (tid + 256) * 8, r1 = f1 >> 5, cc1 = f1 & 31;
    const short* oA0 = Ob  + (size_t)(m0 + r0) * C_ + cc0;   // A: 64 rows (f0 only)
    const short* wA0 = wob + (size_t)(n0 + r0) * C_ + cc0;
    const short* wA1 = wob + (size_t)(n0 + r1) * C_ + cc1;

    f32x4 acc[2][4] = {};

    GLL16(oA0, &As[0][f0]);
    GLL16(wA0, &Bs[0][f0]); GLL16(wA1, &Bs[0][f1]);
    __syncthreads();

    for (int kt = 0; kt < C_ / 32; ++kt) {
        const int cur = kt & 1;
        if (kt + 1 < C_ / 32) {
            int kk = (kt + 1) * 32;
            GLL16(oA0 + kk, &As[cur ^ 1][f0]);
            GLL16(wA0 + kk, &Bs[cur ^ 1][f0]); GLL16(wA1 + kk, &Bs[cur ^ 1][f1]);
        }
        const short* Sa = As[cur];
        const short* Sb = Bs[cur];
        short8 af[2], bf[4];
        #pragma unroll
        for (int mi = 0; mi < 2; ++mi) af[mi] = *(const short8*)&Sa[(wr + mi * 16 + l16) * 32 + quad * 8];
        #pragma unroll
        for (int ni = 0; ni < 4; ++ni) bf[ni] = *(const short8*)&Sb[(wc + ni * 16 + l16) * 32 + quad * 8];
        #pragma unroll
        for (int mi = 0; mi < 2; ++mi)
        #pragma unroll
        for (int ni = 0; ni < 4; ++ni)
            acc[mi][ni] = MFMA(af[mi], bf[ni], acc[mi][ni]);
        __syncthreads();
    }

    #pragma unroll
    for (int mi = 0; mi < 2; ++mi)
    #pragma unroll
    for (int ni = 0; ni < 4; ++ni)
    #pragma unroll
    for (int r = 0; r < 4; ++r) {
        int m = m0 + wr + mi * 16 + quad * 4 + r;
        int c = n0 + wc + ni * 16 + l16;
        out[(size_t)m * C_ + c] = acc[mi][ni][r] + bo[c];
    }
}

extern "C" void kernel_launch(void* const* d_in, const int* in_sizes, int n_in,
                              void* d_out, int out_size, void* d_ws, size_t ws_size,
                              hipStream_t stream) {
    const float* x  = (const float*)d_in[0];
    const float* wq = (const float*)d_in[1];
    const float* wk = (const float*)d_in[2];
    const float* wv = (const float*)d_in[3];
    const float* wo = (const float*)d_in[4];
    const float* bo = (const float*)d_in[5];
    float* out = (float*)d_out;

    short* xb  = (short*)d_ws;        // 4M shorts
    short* Wb  = xb  + 4194304;       // 3M (wq|wk|wv)
    short* wob = Wb  + 3145728;       // 1M
    short* Qb  = wob + 1048576;       // 4M
    short* Kb  = Qb  + 4194304;       // 4M
    short* Vt  = Kb  + 4194304;       // 4M
    short* Obuf= Vt  + 4194304;       // 4M

    dim3 blk(256);
    convert_kernel<<<4096, blk, 0, stream>>>(x, wq, wk, wv, wo, xb);
    qkv_gemm<<<dim3(M_ / 128, 3072 / 128), blk, 0, stream>>>(xb, Wb, Qb, Kb, Vt);
    attn_kernel<<<dim3(N_ / 128, B_ * H_), blk, 0, stream>>>(Qb, Kb, Vt, Obuf);
    proj_gemm<<<dim3(M_ / 64, C_ / 128), blk, 0, stream>>>(Obuf, wob, bo, out);
}

// Round 9
// 190.942 us; speedup vs baseline: 1.0655x; 1.0655x over previous
//
#include <hip/hip_runtime.h>
#include <hip/hip_bf16.h>

typedef float f32x4 __attribute__((ext_vector_type(4)));
typedef short short8 __attribute__((ext_vector_type(8)));
typedef short short4v __attribute__((ext_vector_type(4)));

#define MFMA(a, b, c) __builtin_amdgcn_mfma_f32_16x16x32_bf16((a), (b), (c), 0, 0, 0)

#if __has_builtin(__builtin_amdgcn_exp2f)
#define EXP2(x) __builtin_amdgcn_exp2f(x)
#else
#define EXP2(x) exp2f(x)
#endif

#define B_  2
#define N_  2048
#define C_  1024
#define H_  16
#define HD_ 64
#define M_  (B_ * N_)   // 4096

// softmax scale (1/8) * log2(e), folded into Q at qkv epilogue
#define QSCALE 0.18033688011112042f

typedef const __attribute__((address_space(1))) void* gp_t;
typedef __attribute__((address_space(3))) void* sp_t;
#define GLL16(g, s) __builtin_amdgcn_global_load_lds((gp_t)(const void*)(g), (sp_t)(void*)(s), 16, 0, 0)

__device__ __forceinline__ short f2bf(float f) {
    union { float fv; unsigned u; } v; v.fv = f;
    unsigned r = v.u + 0x7fffu + ((v.u >> 16) & 1u);  // RNE
    return (short)(r >> 16);
}
__device__ __forceinline__ unsigned pack_rne(float a, float b) {
    return (unsigned)(unsigned short)f2bf(a) | ((unsigned)(unsigned short)f2bf(b) << 16);
}

// ---------------- fp32 -> bf16 conversion pass ----------------
__global__ __launch_bounds__(256) void convert_kernel(
    const float* __restrict__ x,  const float* __restrict__ wq,
    const float* __restrict__ wk, const float* __restrict__ wv,
    const float* __restrict__ wo, short* __restrict__ dst)
{
    size_t e = ((size_t)blockIdx.x * 256 + threadIdx.x) * 8;
    const float* src; size_t off;
    if (e < 4194304)      { src = x;  off = e; }
    else if (e < 5242880) { src = wq; off = e - 4194304; }
    else if (e < 6291456) { src = wk; off = e - 5242880; }
    else if (e < 7340032) { src = wv; off = e - 6291456; }
    else                  { src = wo; off = e - 7340032; }
    float4 a = *(const float4*)(src + off);
    float4 b = *(const float4*)(src + off + 4);
    short8 s;
    s[0] = f2bf(a.x); s[1] = f2bf(a.y); s[2] = f2bf(a.z); s[3] = f2bf(a.w);
    s[4] = f2bf(b.x); s[5] = f2bf(b.y); s[6] = f2bf(b.z); s[7] = f2bf(b.w);
    *(short8*)(dst + e) = s;
}

// ---------------- fused QKV GEMM (R3 exact: BK=32, 128x128, 2-barrier) ------
__global__ __launch_bounds__(256) void qkv_gemm(
    const short* __restrict__ xb, const short* __restrict__ Wb,
    short* __restrict__ Qb, short* __restrict__ Kb, short* __restrict__ Vt)
{
    const int m0 = blockIdx.x * 128;
    const int n0 = blockIdx.y * 128;
    __shared__ short As[128 * 32];
    __shared__ short Bs[128 * 32];
    const int tid  = threadIdx.x;
    const int wave = tid >> 6, lane = tid & 63;
    const int quad = lane >> 4, l16 = lane & 15;
    const int wr = (wave >> 1) * 64, wc = (wave & 1) * 64;

    f32x4 acc[4][4] = {};

    for (int kk = 0; kk < C_; kk += 32) {
        __syncthreads();
        #pragma unroll
        for (int it = 0; it < 2; ++it) {
            int f = (it * 256 + tid) * 8;
            int row = f >> 5, col = f & 31;
            GLL16(xb + (size_t)(m0 + row) * C_ + kk + col, &As[f]);
            GLL16(Wb + (size_t)(n0 + row) * C_ + kk + col, &Bs[f]);
        }
        __syncthreads();
        short8 af[4], bf[4];
        #pragma unroll
        for (int mi = 0; mi < 4; ++mi) af[mi] = *(const short8*)&As[(wr + mi * 16 + l16) * 32 + quad * 8];
        #pragma unroll
        for (int ni = 0; ni < 4; ++ni) bf[ni] = *(const short8*)&Bs[(wc + ni * 16 + l16) * 32 + quad * 8];
        #pragma unroll
        for (int mi = 0; mi < 4; ++mi)
        #pragma unroll
        for (int ni = 0; ni < 4; ++ni)
            acc[mi][ni] = MFMA(af[mi], bf[ni], acc[mi][ni]);
    }

    const int which = n0 >> 10;        // block-uniform: 0=Q 1=K 2=V
    const int nb = n0 & 1023;
    #pragma unroll
    for (int mi = 0; mi < 4; ++mi)
    #pragma unroll
    for (int ni = 0; ni < 4; ++ni)
    #pragma unroll
    for (int r = 0; r < 4; ++r) {
        int m  = m0 + wr + mi * 16 + quad * 4 + r;
        int cc = nb + wc + ni * 16 + l16;
        float av = acc[mi][ni][r];
        if (which == 0) av *= QSCALE;
        short bv = f2bf(av);
        int bb = m >> 11, ns = m & (N_ - 1);
        int h = cc >> 6, d = cc & 63;
        size_t bh = (size_t)(bb * H_ + h);
        if (which == 0)      Qb[(bh * N_ + ns) * HD_ + d] = bv;
        else if (which == 1) Kb[(bh * N_ + ns) * HD_ + d] = bv;
        else                 Vt[(bh * HD_ + d) * N_ + ns] = bv;  // V transposed
    }
}

// ---------------- Flash attention ----------------
// R7 staging (GLL16 address-permuted swizzle, dbuf K/V, 1 barrier/tile) +
// permuted-K PV: after S^T for an ni-pair, each lane holds P for
// j in {4q..4q+3} u {16+4q..16+4q+3} == a full 16x16x32 B-fragment under
// permutation pi(8q+t) = (t<4 ? 4q+t : 16+4q+t-4). V^T is read from LDS with
// the same pi (two b64 reads). PV = 16 fast MFMA32; no MFMA16, no shuffles.
__global__ __launch_bounds__(256, 2) void attn_kernel(
    const short* __restrict__ Qb, const short* __restrict__ Kb,
    const short* __restrict__ Vt, short* __restrict__ Ob)
{
    const int bh = blockIdx.y;
    const int b = bh >> 4, h = bh & (H_ - 1);
    const int i0 = blockIdx.x * 128;
    __shared__ short Qs[128 * 64];      // 16 KB
    __shared__ short Ks[2][64 * 64];    // 16 KB
    __shared__ short Vs[2][64 * 64];    // 16 KB, Vs[d][j]
    const int tid  = threadIdx.x;
    const int wave = tid >> 6, lane = tid & 63;
    const int quad = lane >> 4, l16 = lane & 15;
    const int sw = l16 & 7;             // frag-read swizzle key (row&7 == l16&7)

    const short* Qg = Qb + ((size_t)bh * N_ + i0) * HD_;
    const short* Kg = Kb + (size_t)bh * N_ * HD_;
    const short* Vg = Vt + (size_t)bh * HD_ * N_;

    const int row0 = tid >> 3,  c0 = (tid & 7) ^ (row0 & 7);
    const int row1 = row0 + 32, c1 = (tid & 7) ^ (row1 & 7);
    const short* KgA0 = Kg + row0 * HD_ + c0 * 8;
    const short* KgA1 = Kg + row1 * HD_ + c1 * 8;
    const short* VgA0 = Vg + (size_t)row0 * N_ + c0 * 8;
    const short* VgA1 = Vg + (size_t)row1 * N_ + c1 * 8;

    #pragma unroll
    for (int it = 0; it < 4; ++it) {
        int s = it * 256 + tid;
        int row = s >> 3, c = (s & 7) ^ (row & 7);
        GLL16(Qg + row * HD_ + c * 8, &Qs[s * 8]);
    }
    GLL16(KgA0, &Ks[0][tid * 8]);
    GLL16(KgA1, &Ks[0][(tid + 256) * 8]);
    GLL16(VgA0, &Vs[0][tid * 8]);
    GLL16(VgA1, &Vs[0][(tid + 256) * 8]);
    __syncthreads();

    short8 qf[2][2];
    #pragma unroll
    for (int s = 0; s < 2; ++s) {
        int row = (wave * 32 + s * 16 + l16) * 64;
        qf[s][0] = *(const short8*)&Qs[row + ((quad ^ sw) * 8)];
        qf[s][1] = *(const short8*)&Qs[row + (((quad + 4) ^ sw) * 8)];
    }

    f32x4 o[2][4] = {};
    float lrow[2] = {0.f, 0.f};

    for (int jt = 0; jt < N_ / 64; ++jt) {
        const int cur = jt & 1;
        if (jt + 1 < N_ / 64) {
            int j1 = (jt + 1) * 64;
            GLL16(KgA0 + (size_t)j1 * HD_, &Ks[cur ^ 1][tid * 8]);
            GLL16(KgA1 + (size_t)j1 * HD_, &Ks[cur ^ 1][(tid + 256) * 8]);
            GLL16(VgA0 + j1, &Vs[cur ^ 1][tid * 8]);
            GLL16(VgA1 + j1, &Vs[cur ^ 1][(tid + 256) * 8]);
        }
        const short* Kc = Ks[cur];
        const short* Vc = Vs[cur];

        #pragma unroll
        for (int half = 0; half < 2; ++half) {
            // S^T for ni = 2*half, 2*half+1; P stays in registers as the
            // permuted B-fragment of a 16x16x32 PV MFMA.
            unsigned pq[2][4];
            #pragma unroll
            for (int nio = 0; nio < 2; ++nio) {
                int ni = half * 2 + nio;
                int krow = (ni * 16 + l16) * 64;
                short8 kf0 = *(const short8*)&Kc[krow + ((quad ^ sw) * 8)];
                short8 kf1 = *(const short8*)&Kc[krow + (((quad + 4) ^ sw) * 8)];
                #pragma unroll
                for (int s = 0; s < 2; ++s) {
                    f32x4 st = {0.f, 0.f, 0.f, 0.f};
                    st = MFMA(kf0, qf[s][0], st);
                    st = MFMA(kf1, qf[s][1], st);   // S^T[j=16ni+4q+r][i=strip+l16]
                    union { float f; unsigned u; } e0, e1, e2, e3;
                    e0.f = EXP2(st[0]); e1.f = EXP2(st[1]);
                    e2.f = EXP2(st[2]); e3.f = EXP2(st[3]);
                    lrow[s] += (e0.f + e1.f) + (e2.f + e3.f);
                    pq[s][nio * 2]     = (e0.u >> 16) | (e1.u & 0xffff0000u);
                    pq[s][nio * 2 + 1] = (e2.u >> 16) | (e3.u & 0xffff0000u);
                }
            }
            // PV: A = V^T under the same permutation (two b64 reads / di),
            // shared across strips; B = pq.
            #pragma unroll
            for (int di = 0; di < 4; ++di) {
                int vrow = (di * 16 + l16) * 64;
                int ch1 = (half * 4 +     (quad >> 1)) ^ sw;
                int ch2 = (half * 4 + 2 + (quad >> 1)) ^ sw;
                union { struct { short4v lo, hi; } p; short8 v; } va;
                va.p.lo = *(const short4v*)&Vc[vrow + ch1 * 8 + (quad & 1) * 4];
                va.p.hi = *(const short4v*)&Vc[vrow + ch2 * 8 + (quad & 1) * 4];
                #pragma unroll
                for (int s = 0; s < 2; ++s) {
                    union { unsigned u[4]; short8 v; } pb;
                    pb.u[0] = pq[s][0]; pb.u[1] = pq[s][1];
                    pb.u[2] = pq[s][2]; pb.u[3] = pq[s][3];
                    o[s][di] = MFMA(va.v, pb.v, o[s][di]);
                }
            }
        }
        __syncthreads();
    }

    #pragma unroll
    for (int s = 0; s < 2; ++s) {
        float l = lrow[s];
        l += __shfl_xor(l, 16, 64);
        l += __shfl_xor(l, 32, 64);
        float inv = 1.f / l;
        int ig = i0 + wave * 32 + s * 16 + l16;
        size_t base = ((size_t)(b * N_ + ig)) * C_ + h * HD_;
        #pragma unroll
        for (int di = 0; di < 4; ++di) {
            // O^T: d = di*16 + quad*4 + r, i = l16
            unsigned p01 = pack_rne(o[s][di][0] * inv, o[s][di][1] * inv);
            unsigned p23 = pack_rne(o[s][di][2] * inv, o[s][di][3] * inv);
            *(unsigned*)&Ob[base + di * 16 + quad * 4]     = p01;
            *(unsigned*)&Ob[base + di * 16 + quad * 4 + 2] = p23;
        }
    }
}

// ---------------- Output projection (R3 exact: BK=32, 64x128, 2-barrier) ----
__global__ __launch_bounds__(256) void proj_gemm(
    const short* __restrict__ Ob, const short* __restrict__ wob,
    const float* __restrict__ bo, float* __restrict__ out)
{
    const int m0 = blockIdx.x * 64;
    const int n0 = blockIdx.y * 128;
    __shared__ short As[64 * 32];
    __shared__ short Bs[128 * 32];
    const int tid  = threadIdx.x;
    const int wave = tid >> 6, lane = tid & 63;
    const int quad = lane >> 4, l16 = lane & 15;
    const int wr = (wave >> 1) * 32, wc = (wave & 1) * 64;

    f32x4 acc[2][4] = {};

    for (int kk = 0; kk < C_; kk += 32) {
        __syncthreads();
        {
            int f = tid * 8;
            int row = f >> 5, col = f & 31;
            GLL16(Ob + (size_t)(m0 + row) * C_ + kk + col, &As[f]);
        }
        #pragma unroll
        for (int it = 0; it < 2; ++it) {
            int f = (it * 256 + tid) * 8;
            int row = f >> 5, col = f & 31;
            GLL16(wob + (size_t)(n0 + row) * C_ + kk + col, &Bs[f]);
        }
        __syncthreads();
        short8 af[2], bf[4];
        #pragma unroll
        for (int mi = 0; mi < 2; ++mi) af[mi] = *(const short8*)&As[(wr + mi * 16 + l16) * 32 + quad * 8];
        #pragma unroll
        for (int ni = 0; ni < 4; ++ni) bf[ni] = *(const short8*)&Bs[(wc + ni * 16 + l16) * 32 + quad * 8];
        #pragma unroll
        for (int mi = 0; mi < 2; ++mi)
        #pragma unroll
        for (int ni = 0; ni < 4; ++ni)
            acc[mi][ni] = MFMA(af[mi], bf[ni], acc[mi][ni]);
    }

    #pragma unroll
    for (int mi = 0; mi < 2; ++mi)
    #pragma unroll
    for (int ni = 0; ni < 4; ++ni)
    #pragma unroll
    for (int r = 0; r < 4; ++r) {
        int m = m0 + wr + mi * 16 + quad * 4 + r;
        int c = n0 + wc + ni * 16 + l16;
        out[(size_t)m * C_ + c] = acc[mi][ni][r] + bo[c];
    }
}

extern "C" void kernel_launch(void* const* d_in, const int* in_sizes, int n_in,
                              void* d_out, int out_size, void* d_ws, size_t ws_size,
                              hipStream_t stream) {
    const float* x  = (const float*)d_in[0];
    const float* wq = (const float*)d_in[1];
    const float* wk = (const float*)d_in[2];
    const float* wv = (const float*)d_in[3];
    const float* wo = (const float*)d_in[4];
    const float* bo = (const float*)d_in[5];
    float* out = (float*)d_out;

    short* xb  = (short*)d_ws;        // 4M shorts
    short* Wb  = xb  + 4194304;       // 3M (wq|wk|wv)
    short* wob = Wb  + 3145728;       // 1M
    short* Qb  = wob + 1048576;       // 4M
    short* Kb  = Qb  + 4194304;       // 4M
    short* Vt  = Kb  + 4194304;       // 4M
    short* Obuf= Vt  + 4194304;       // 4M

    dim3 blk(256);
    convert_kernel<<<4096, blk, 0, stream>>>(x, wq, wk, wv, wo, xb);
    qkv_gemm<<<dim3(M_ / 128, 3072 / 128), blk, 0, stream>>>(xb, Wb, Qb, Kb, Vt);
    attn_kernel<<<dim3(N_ / 128, B_ * H_), blk, 0, stream>>>(Qb, Kb, Vt, Obuf);
    proj_gemm<<<dim3(M_ / 64, C_ / 128), blk, 0, stream>>>(Obuf, wob, bo, out);
}